// Round 6
// baseline (250.236 us; speedup 1.0000x reference)
//
#include <hip/hip_runtime.h>

typedef unsigned short u16;
typedef unsigned int u32;
typedef __attribute__((ext_vector_type(8))) short bf16x8;
typedef __attribute__((ext_vector_type(4))) float f32x4;

#define B_ 4
#define H_ 12
#define N_ 2048
#define D_ 768
#define HD_ 64
#define NTOK (B_ * N_)      /* 8192 */
#define NE   (H_ * 3 * HD_) /* 2304 */

#define BM 128
#define BN 128
#define BK 64

// 1/sqrt(64) * log2(e): Q pre-scale so attention uses exp2 (bare v_exp_f32)
#define QSCALE 0.18033688011112042f

__device__ __forceinline__ u16 f2bf(float f) {
    u32 u = __float_as_uint(f);
    u += 0x7fffu + ((u >> 16) & 1u);
    return (u16)(u >> 16);
}

__device__ __forceinline__ f32x4 mfma16(bf16x8 a, bf16x8 b, f32x4 c) {
    return __builtin_amdgcn_mfma_f32_16x16x32_bf16(a, b, c, 0, 0, 0);
}

// async global->LDS, 16B per lane. LDS dest = wave-uniform base + lane*16.
__device__ __forceinline__ void g2l16(const u16* g, u16* l) {
    __builtin_amdgcn_global_load_lds(
        (const __attribute__((address_space(1))) void*)g,
        (__attribute__((address_space(3))) void*)l, 16, 0, 0);
}

// ---------------- f32 -> bf16 conversion ----------------
__global__ __launch_bounds__(256) void cvt_bf16(const float* __restrict__ in,
                                                u16* __restrict__ out, int n4) {
    int i = blockIdx.x * blockDim.x + threadIdx.x;
    if (i < n4) {
        float4 v = ((const float4*)in)[i];
        u32 lo = (u32)f2bf(v.x) | ((u32)f2bf(v.y) << 16);
        u32 hi = (u32)f2bf(v.z) | ((u32)f2bf(v.w) << 16);
        ((uint2*)out)[i] = make_uint2(lo, hi);
    }
}

// ============ m97-structure GEMM core (shared by both epilogues) ============
#define GEMM_CORE(Xp, Wp)                                                      \
    __shared__ u16 ldsA[BM * BK];                                              \
    __shared__ u16 ldsB[BN * BK];                                              \
    const int tid = threadIdx.x;                                               \
    const int wave = tid >> 6, lane = tid & 63;                                \
    const int lrow = lane & 15, quad = lane >> 4;                              \
    const int mbase = blockIdx.x * BM;                                         \
    const int nbase = blockIdx.y * BN;                                         \
    const int srow = tid >> 3;      /* 0..31 */                                \
    const int schunk = tid & 7;                                                \
    const int sk = (schunk ^ (srow & 7)) << 3; /* swizzled global k-offset */  \
    const int sdst = srow * BK + schunk * 8;   /* lane-contiguous LDS dest */  \
    const u16* gA = Xp + (size_t)(mbase + srow) * D_ + sk;                     \
    const u16* gB = Wp + (size_t)(nbase + srow) * D_ + sk;                     \
    const int m_ofs = (wave >> 1) * 64;                                        \
    const int n_ofs = (wave & 1) * 64;                                         \
    const int e_ = lrow & 7;                                                   \
    const int offA0 = (m_ofs + lrow) * BK + ((quad ^ e_) << 3);                \
    const int offB0 = (n_ofs + lrow) * BK + ((quad ^ e_) << 3);                \
    f32x4 acc[4][4] = {};                                                      \
    for (int kt = 0; kt < D_; kt += BK) {                                      \
        __syncthreads();                                                       \
        _Pragma("unroll") for (int i = 0; i < 4; i++) {                        \
            g2l16(gA + (size_t)(32 * i) * D_ + kt, ldsA + sdst + i * 32 * BK); \
            g2l16(gB + (size_t)(32 * i) * D_ + kt, ldsB + sdst + i * 32 * BK); \
        }                                                                      \
        __syncthreads();                                                       \
        _Pragma("unroll") for (int ks = 0; ks < 2; ks++) {                     \
            const int oa = offA0 ^ (ks << 5);                                  \
            const int ob = offB0 ^ (ks << 5);                                  \
            bf16x8 af[4], bfr[4];                                              \
            _Pragma("unroll") for (int c = 0; c < 4; c++)                      \
                af[c] = *(const bf16x8*)&ldsA[oa + c * 16 * BK];               \
            _Pragma("unroll") for (int c = 0; c < 4; c++)                      \
                bfr[c] = *(const bf16x8*)&ldsB[ob + c * 16 * BK];              \
            _Pragma("unroll") for (int i = 0; i < 4; i++)                      \
                _Pragma("unroll") for (int j = 0; j < 4; j++)                  \
                    acc[i][j] = mfma16(af[i], bfr[j], acc[i][j]);              \
        }                                                                      \
    }

// ---------------- QKV projection GEMM ----------------
__global__ __launch_bounds__(256) void gemm_qkv(const u16* __restrict__ X,
                                                const u16* __restrict__ W,
                                                const float* __restrict__ bqkv,
                                                u16* __restrict__ Qs,
                                                u16* __restrict__ Ks,
                                                u16* __restrict__ Vt) {
    GEMM_CORE(X, W)
#pragma unroll
    for (int cn = 0; cn < 4; cn++) {
        const int E = nbase + n_ofs + cn * 16;
        const int h = E / 192;
        const int rr = E - h * 192;
        const int kind = rr >> 6;               // 0=Q 1=K 2=V
        const int d = (rr & 63) + lrow;
        const float bias = bqkv[E + lrow];
#pragma unroll
        for (int cm = 0; cm < 4; cm++) {
#pragma unroll
            for (int r = 0; r < 4; r++) {
                const int t = mbase + m_ofs + cm * 16 + quad * 4 + r;
                const int b_ = t >> 11, n = t & (N_ - 1);
                const size_t bh = (size_t)(b_ * H_ + h);
                const float val = acc[cm][cn][r] + bias;
                if (kind == 0) {
                    Qs[(bh * N_ + n) * HD_ + d] = f2bf(val * QSCALE);
                } else if (kind == 1) {
                    Ks[(bh * N_ + n) * HD_ + d] = f2bf(val);
                } else {
                    Vt[(bh * HD_ + d) * N_ + n] = f2bf(val);
                }
            }
        }
    }
}

// ---------------- output projection GEMM ----------------
__global__ __launch_bounds__(256) void gemm_out(const u16* __restrict__ X2,
                                                const u16* __restrict__ W,
                                                const float* __restrict__ bmsa,
                                                float* __restrict__ out) {
    GEMM_CORE(X2, W)
#pragma unroll
    for (int cn = 0; cn < 4; cn++) {
        const int col = nbase + n_ofs + cn * 16 + lrow;
        const float bias = bmsa[col];
#pragma unroll
        for (int cm = 0; cm < 4; cm++) {
#pragma unroll
            for (int r = 0; r < 4; r++) {
                const int t = mbase + m_ofs + cm * 16 + quad * 4 + r;
                out[(size_t)t * D_ + col] = acc[cm][cn][r] + bias;
            }
        }
    }
}

// ---------------- Flash attention v5: VALU-lean softmax ----------------
// R5 showed VALUBusy 44% == the softmax ALU chain; v_exp_f32 alone is
// ~41 us. Cuts: (1) log2e folded into Q scale -> bare exp2; (2) row sums
// via MFMA against a ones-fragment (replaces 201M VALU adds + epilogue
// shuffles; l is consistent with the bf16 P used in PV); (3) 2-instr
// round-half-up bf16 pack. Per element: 1 trans + 2 VALU + 1 ds_write_b16.
__global__ __launch_bounds__(256, 3) void flash_attn(const u16* __restrict__ Qs,
                                                     const u16* __restrict__ Ks,
                                                     const u16* __restrict__ Vt,
                                                     u16* __restrict__ X2) {
    __shared__ u16 ldsK[2][64 * HD_];   // 2 x 8 KB
    __shared__ u16 ldsV[2][64 * HD_];   // 2 x 8 KB
    __shared__ u16 ldsP[4][2][16][68];  // 17 KB, wave-private P transpose
    const int tid = threadIdx.x;
    const int wave = tid >> 6, lane = tid & 63;
    const int lrow = lane & 15, quad = lane >> 4;
    const int qbase = blockIdx.x * 128 + wave * 32;
    const int bh = blockIdx.y;
    const int b = bh / H_, h = bh - b * H_;

    const u16* Kb = Ks + (size_t)bh * N_ * HD_;
    const u16* Vb = Vt + (size_t)bh * HD_ * N_;

    const int srow = tid >> 3;
    const int schunk = tid & 7;
    const int skk = (schunk ^ (srow & 7)) << 3;
    const int sdst = srow * HD_ + schunk * 8;

    bf16x8 qa[2][2];
#pragma unroll
    for (int t = 0; t < 2; t++) {
        const u16* Qb = Qs + ((size_t)bh * N_ + qbase + t * 16 + lrow) * HD_ + quad * 8;
        qa[t][0] = *(const bf16x8*)(Qb);
        qa[t][1] = *(const bf16x8*)(Qb + 32);
    }

    const int fofs = (quad ^ (lrow & 7)) << 3;
    const short onebf = (short)0x3F80;  // bf16 1.0
    const bf16x8 ones = {onebf, onebf, onebf, onebf, onebf, onebf, onebf, onebf};

    f32x4 Oacc[2][4] = {};
    f32x4 lacc[2] = {};

    {   // prologue: stage tile 0 into buffer 0
        const u16* gK = Kb + (size_t)srow * HD_ + skk;
        g2l16(gK, &ldsK[0][sdst]);
        g2l16(gK + (size_t)32 * HD_, &ldsK[0][sdst + 32 * HD_]);
        const u16* gV = Vb + (size_t)srow * N_ + skk;
        g2l16(gV, &ldsV[0][sdst]);
        g2l16(gV + (size_t)32 * N_, &ldsV[0][sdst + 32 * HD_]);
    }

    for (int it = 0; it < N_ / 64; it++) {
        const int cur = it & 1;
        __syncthreads();  // drains DMA for buf[cur]; waves done with buf[cur^1]
        if (it + 1 < N_ / 64) {
            const int kt2 = (it + 1) << 6;
            const u16* gK = Kb + (size_t)(kt2 + srow) * HD_ + skk;
            g2l16(gK, &ldsK[cur ^ 1][sdst]);
            g2l16(gK + (size_t)32 * HD_, &ldsK[cur ^ 1][sdst + 32 * HD_]);
            const u16* gV = Vb + (size_t)srow * N_ + kt2 + skk;
            g2l16(gV, &ldsV[cur ^ 1][sdst]);
            g2l16(gV + (size_t)32 * N_, &ldsV[cur ^ 1][sdst + 32 * HD_]);
        }
        // ---- K fragments from LDS ----
        bf16x8 kf[8];
#pragma unroll
        for (int c = 0; c < 4; c++) {
            const int o = (c * 16 + lrow) * HD_ + fofs;
            kf[2 * c]     = *(const bf16x8*)&ldsK[cur][o];
            kf[2 * c + 1] = *(const bf16x8*)&ldsK[cur][o ^ 32];
        }
        // ---- S = Q K^T (log2e pre-folded) ----
        f32x4 s[2][4] = {};
#pragma unroll
        for (int t = 0; t < 2; t++)
#pragma unroll
            for (int c = 0; c < 4; c++) {
                s[t][c] = mfma16(qa[t][0], kf[2 * c], s[t][c]);
                s[t][c] = mfma16(qa[t][1], kf[2 * c + 1], s[t][c]);
            }
        // ---- P = 2^S, round-half-up to bf16, store to wave-private LDS ----
#pragma unroll
        for (int t = 0; t < 2; t++)
#pragma unroll
            for (int c = 0; c < 4; c++)
#pragma unroll
                for (int r = 0; r < 4; r++) {
                    float p = __builtin_exp2f(s[t][c][r]);
                    ldsP[wave][t][quad * 4 + r][c * 16 + lrow] =
                        (u16)((__float_as_uint(p) + 0x8000u) >> 16);
                }
        bf16x8 pa[2][2];
#pragma unroll
        for (int t = 0; t < 2; t++) {
            pa[t][0] = *(const bf16x8*)&ldsP[wave][t][lrow][quad * 8];
            pa[t][1] = *(const bf16x8*)&ldsP[wave][t][lrow][32 + quad * 8];
        }
        // ---- row sums via MFMA (every lane in a row group gets the sum) ----
#pragma unroll
        for (int t = 0; t < 2; t++) {
            lacc[t] = mfma16(pa[t][0], ones, lacc[t]);
            lacc[t] = mfma16(pa[t][1], ones, lacc[t]);
        }
        // ---- V fragments from LDS; O += P V ----
#pragma unroll
        for (int c = 0; c < 4; c++) {
            const int o = (c * 16 + lrow) * HD_ + fofs;
            bf16x8 v0 = *(const bf16x8*)&ldsV[cur][o];
            bf16x8 v1 = *(const bf16x8*)&ldsV[cur][o ^ 32];
#pragma unroll
            for (int t = 0; t < 2; t++) {
                Oacc[t][c] = mfma16(pa[t][0], v0, Oacc[t][c]);
                Oacc[t][c] = mfma16(pa[t][1], v1, Oacc[t][c]);
            }
        }
    }
    // ---- epilogue: no shuffles; lacc[t][r] is the row sum ----
#pragma unroll
    for (int t = 0; t < 2; t++)
#pragma unroll
        for (int r = 0; r < 4; r++) {
            const float inv = 1.0f / lacc[t][r];
            const int qrow = qbase + t * 16 + quad * 4 + r;
#pragma unroll
            for (int c = 0; c < 4; c++) {
                X2[((size_t)b * N_ + qrow) * D_ + h * HD_ + c * 16 + lrow] =
                    f2bf(Oacc[t][c][r] * inv);
            }
        }
}

extern "C" void kernel_launch(void* const* d_in, const int* in_sizes, int n_in,
                              void* d_out, int out_size, void* d_ws, size_t ws_size,
                              hipStream_t stream) {
    const float* z    = (const float*)d_in[0];
    const float* Wqkv = (const float*)d_in[1];
    const float* bqkv = (const float*)d_in[2];
    const float* Wmsa = (const float*)d_in[3];
    const float* bmsa = (const float*)d_in[4];
    float* out = (float*)d_out;

    u16* Xbf = (u16*)d_ws;
    u16* Wqb = Xbf + (size_t)NTOK * D_;
    u16* Wmb = Wqb + (size_t)NE * D_;
    u16* Qs  = Wmb + (size_t)D_ * D_;
    u16* Ks  = Qs + (size_t)B_ * H_ * N_ * HD_;
    u16* Vt  = Ks + (size_t)B_ * H_ * N_ * HD_;
    u16* X2  = Vt + (size_t)B_ * H_ * N_ * HD_;

    const int nz = NTOK * D_ / 4;
    const int nwq = NE * D_ / 4;
    const int nwm = D_ * D_ / 4;
    cvt_bf16<<<(nz + 255) / 256, 256, 0, stream>>>(z, Xbf, nz);
    cvt_bf16<<<(nwq + 255) / 256, 256, 0, stream>>>(Wqkv, Wqb, nwq);
    cvt_bf16<<<(nwm + 255) / 256, 256, 0, stream>>>(Wmsa, Wmb, nwm);

    gemm_qkv<<<dim3(NTOK / BM, NE / BN), 256, 0, stream>>>(Xbf, Wqb, bqkv, Qs, Ks, Vt);
    flash_attn<<<dim3(N_ / 128, B_ * H_), 256, 0, stream>>>(Qs, Ks, Vt, X2);
    gemm_out<<<dim3(NTOK / BM, D_ / BN), 256, 0, stream>>>(X2, Wmb, bmsa, out);
}

// Round 7
// 228.922 us; speedup vs baseline: 1.0931x; 1.0931x over previous
//
#include <hip/hip_runtime.h>

typedef unsigned short u16;
typedef unsigned int u32;
typedef __attribute__((ext_vector_type(8))) short bf16x8;
typedef __attribute__((ext_vector_type(4))) float f32x4;

#define B_ 4
#define H_ 12
#define N_ 2048
#define D_ 768
#define HD_ 64
#define NTOK (B_ * N_)      /* 8192 */
#define NE   (H_ * 3 * HD_) /* 2304 */

#define BM 128
#define BN 128
#define BK 64

// 1/sqrt(64) * log2(e): Q pre-scale so attention uses exp2 (bare v_exp_f32)
#define QSCALE 0.18033688011112042f

__device__ __forceinline__ u16 f2bf(float f) {
    u32 u = __float_as_uint(f);
    u += 0x7fffu + ((u >> 16) & 1u);
    return (u16)(u >> 16);
}

__device__ __forceinline__ f32x4 mfma16(bf16x8 a, bf16x8 b, f32x4 c) {
    return __builtin_amdgcn_mfma_f32_16x16x32_bf16(a, b, c, 0, 0, 0);
}

// async global->LDS, 16B per lane. LDS dest = wave-uniform base + lane*16.
__device__ __forceinline__ void g2l16(const u16* g, u16* l) {
    __builtin_amdgcn_global_load_lds(
        (const __attribute__((address_space(1))) void*)g,
        (__attribute__((address_space(3))) void*)l, 16, 0, 0);
}

// ---------------- f32 -> bf16 conversion ----------------
__global__ __launch_bounds__(256) void cvt_bf16(const float* __restrict__ in,
                                                u16* __restrict__ out, int n4) {
    int i = blockIdx.x * blockDim.x + threadIdx.x;
    if (i < n4) {
        float4 v = ((const float4*)in)[i];
        u32 lo = (u32)f2bf(v.x) | ((u32)f2bf(v.y) << 16);
        u32 hi = (u32)f2bf(v.z) | ((u32)f2bf(v.w) << 16);
        ((uint2*)out)[i] = make_uint2(lo, hi);
    }
}

// ============ m97-structure GEMM core (shared by both epilogues) ============
#define GEMM_CORE(Xp, Wp)                                                      \
    __shared__ u16 ldsA[BM * BK];                                              \
    __shared__ u16 ldsB[BN * BK];                                              \
    const int tid = threadIdx.x;                                               \
    const int wave = tid >> 6, lane = tid & 63;                                \
    const int lrow = lane & 15, quad = lane >> 4;                              \
    const int mbase = blockIdx.x * BM;                                         \
    const int nbase = blockIdx.y * BN;                                         \
    const int srow = tid >> 3;      /* 0..31 */                                \
    const int schunk = tid & 7;                                                \
    const int sk = (schunk ^ (srow & 7)) << 3; /* swizzled global k-offset */  \
    const int sdst = srow * BK + schunk * 8;   /* lane-contiguous LDS dest */  \
    const u16* gA = Xp + (size_t)(mbase + srow) * D_ + sk;                     \
    const u16* gB = Wp + (size_t)(nbase + srow) * D_ + sk;                     \
    const int m_ofs = (wave >> 1) * 64;                                        \
    const int n_ofs = (wave & 1) * 64;                                         \
    const int e_ = lrow & 7;                                                   \
    const int offA0 = (m_ofs + lrow) * BK + ((quad ^ e_) << 3);                \
    const int offB0 = (n_ofs + lrow) * BK + ((quad ^ e_) << 3);                \
    f32x4 acc[4][4] = {};                                                      \
    for (int kt = 0; kt < D_; kt += BK) {                                      \
        __syncthreads();                                                       \
        _Pragma("unroll") for (int i = 0; i < 4; i++) {                        \
            g2l16(gA + (size_t)(32 * i) * D_ + kt, ldsA + sdst + i * 32 * BK); \
            g2l16(gB + (size_t)(32 * i) * D_ + kt, ldsB + sdst + i * 32 * BK); \
        }                                                                      \
        __syncthreads();                                                       \
        _Pragma("unroll") for (int ks = 0; ks < 2; ks++) {                     \
            const int oa = offA0 ^ (ks << 5);                                  \
            const int ob = offB0 ^ (ks << 5);                                  \
            bf16x8 af[4], bfr[4];                                              \
            _Pragma("unroll") for (int c = 0; c < 4; c++)                      \
                af[c] = *(const bf16x8*)&ldsA[oa + c * 16 * BK];               \
            _Pragma("unroll") for (int c = 0; c < 4; c++)                      \
                bfr[c] = *(const bf16x8*)&ldsB[ob + c * 16 * BK];              \
            _Pragma("unroll") for (int i = 0; i < 4; i++)                      \
                _Pragma("unroll") for (int j = 0; j < 4; j++)                  \
                    acc[i][j] = mfma16(af[i], bfr[j], acc[i][j]);              \
        }                                                                      \
    }

// ---------------- QKV projection GEMM ----------------
__global__ __launch_bounds__(256) void gemm_qkv(const u16* __restrict__ X,
                                                const u16* __restrict__ W,
                                                const float* __restrict__ bqkv,
                                                u16* __restrict__ Qs,
                                                u16* __restrict__ Ks,
                                                u16* __restrict__ Vt) {
    GEMM_CORE(X, W)
#pragma unroll
    for (int cn = 0; cn < 4; cn++) {
        const int E = nbase + n_ofs + cn * 16;
        const int h = E / 192;
        const int rr = E - h * 192;
        const int kind = rr >> 6;               // 0=Q 1=K 2=V
        const int d = (rr & 63) + lrow;
        const float bias = bqkv[E + lrow];
#pragma unroll
        for (int cm = 0; cm < 4; cm++) {
#pragma unroll
            for (int r = 0; r < 4; r++) {
                const int t = mbase + m_ofs + cm * 16 + quad * 4 + r;
                const int b_ = t >> 11, n = t & (N_ - 1);
                const size_t bh = (size_t)(b_ * H_ + h);
                const float val = acc[cm][cn][r] + bias;
                if (kind == 0) {
                    Qs[(bh * N_ + n) * HD_ + d] = f2bf(val * QSCALE);
                } else if (kind == 1) {
                    Ks[(bh * N_ + n) * HD_ + d] = f2bf(val);
                } else {
                    Vt[(bh * HD_ + d) * N_ + n] = f2bf(val);
                }
            }
        }
    }
}

// ---------------- output projection GEMM ----------------
__global__ __launch_bounds__(256) void gemm_out(const u16* __restrict__ X2,
                                                const u16* __restrict__ W,
                                                const float* __restrict__ bmsa,
                                                float* __restrict__ out) {
    GEMM_CORE(X2, W)
#pragma unroll
    for (int cn = 0; cn < 4; cn++) {
        const int col = nbase + n_ofs + cn * 16 + lrow;
        const float bias = bmsa[col];
#pragma unroll
        for (int cm = 0; cm < 4; cm++) {
#pragma unroll
            for (int r = 0; r < 4; r++) {
                const int t = mbase + m_ofs + cm * 16 + quad * 4 + r;
                out[(size_t)t * D_ + col] = acc[cm][cn][r] + bias;
            }
        }
    }
}

// ---------------- Flash attention v6 ----------------
// R6 lesson: __builtin_exp2f -> OCML accurate exp2 (+12us VALU). Use the raw
// intrinsic __builtin_amdgcn_exp2f (single v_exp_f32).
// New: compute S^T = K*Q^T (operand swap; identical LDS reads since A/B frag
// address patterns coincide). A lane's 4 acc values are then 4 CONSECUTIVE
// keys for one q -> P-transpose write is 8x ds_write_b64 (v_perm-packed)
// instead of 32x ds_write_b16. PV reads / ones-MFMA row sums / O layout
// unchanged.
__global__ __launch_bounds__(256, 3) void flash_attn(const u16* __restrict__ Qs,
                                                     const u16* __restrict__ Ks,
                                                     const u16* __restrict__ Vt,
                                                     u16* __restrict__ X2) {
    __shared__ u16 ldsK[2][64 * HD_];   // 2 x 8 KB
    __shared__ u16 ldsV[2][64 * HD_];   // 2 x 8 KB
    __shared__ u16 ldsP[4][2][16][68];  // row = q (0..15), col = key (0..63)+pad
    const int tid = threadIdx.x;
    const int wave = tid >> 6, lane = tid & 63;
    const int lrow = lane & 15, quad = lane >> 4;
    const int qbase = blockIdx.x * 128 + wave * 32;
    const int bh = blockIdx.y;
    const int b = bh / H_, h = bh - b * H_;

    const u16* Kb = Ks + (size_t)bh * N_ * HD_;
    const u16* Vb = Vt + (size_t)bh * HD_ * N_;

    const int srow = tid >> 3;
    const int schunk = tid & 7;
    const int skk = (schunk ^ (srow & 7)) << 3;
    const int sdst = srow * HD_ + schunk * 8;

    // Q fragments: serve as B-operand (B[k=d][n=q]) — same addresses as A-frag
    bf16x8 qa[2][2];
#pragma unroll
    for (int t = 0; t < 2; t++) {
        const u16* Qb = Qs + ((size_t)bh * N_ + qbase + t * 16 + lrow) * HD_ + quad * 8;
        qa[t][0] = *(const bf16x8*)(Qb);
        qa[t][1] = *(const bf16x8*)(Qb + 32);
    }

    const int fofs = (quad ^ (lrow & 7)) << 3;
    const short onebf = (short)0x3F80;  // bf16 1.0
    const bf16x8 ones = {onebf, onebf, onebf, onebf, onebf, onebf, onebf, onebf};

    f32x4 Oacc[2][4] = {};
    f32x4 lacc[2] = {};

    {   // prologue: stage tile 0 into buffer 0
        const u16* gK = Kb + (size_t)srow * HD_ + skk;
        g2l16(gK, &ldsK[0][sdst]);
        g2l16(gK + (size_t)32 * HD_, &ldsK[0][sdst + 32 * HD_]);
        const u16* gV = Vb + (size_t)srow * N_ + skk;
        g2l16(gV, &ldsV[0][sdst]);
        g2l16(gV + (size_t)32 * N_, &ldsV[0][sdst + 32 * HD_]);
    }

    for (int it = 0; it < N_ / 64; it++) {
        const int cur = it & 1;
        __syncthreads();  // drains DMA for buf[cur]; waves done with buf[cur^1]
        if (it + 1 < N_ / 64) {
            const int kt2 = (it + 1) << 6;
            const u16* gK = Kb + (size_t)(kt2 + srow) * HD_ + skk;
            g2l16(gK, &ldsK[cur ^ 1][sdst]);
            g2l16(gK + (size_t)32 * HD_, &ldsK[cur ^ 1][sdst + 32 * HD_]);
            const u16* gV = Vb + (size_t)srow * N_ + kt2 + skk;
            g2l16(gV, &ldsV[cur ^ 1][sdst]);
            g2l16(gV + (size_t)32 * N_, &ldsV[cur ^ 1][sdst + 32 * HD_]);
        }
        // ---- K fragments from LDS (A-operand: A[m=key][k=d]) ----
        bf16x8 kf[8];
#pragma unroll
        for (int c = 0; c < 4; c++) {
            const int o = (c * 16 + lrow) * HD_ + fofs;
            kf[2 * c]     = *(const bf16x8*)&ldsK[cur][o];
            kf[2 * c + 1] = *(const bf16x8*)&ldsK[cur][o ^ 32];
        }
        // ---- S^T = K Q^T : lane holds (key=c*16+quad*4+r, q=lrow) ----
        f32x4 s[2][4] = {};
#pragma unroll
        for (int t = 0; t < 2; t++)
#pragma unroll
            for (int c = 0; c < 4; c++) {
                s[t][c] = mfma16(kf[2 * c], qa[t][0], s[t][c]);
                s[t][c] = mfma16(kf[2 * c + 1], qa[t][1], s[t][c]);
            }
        // ---- P = 2^S (raw v_exp_f32), pack 4 consecutive keys -> b64 store ----
#pragma unroll
        for (int t = 0; t < 2; t++)
#pragma unroll
            for (int c = 0; c < 4; c++) {
                u32 a0 = __float_as_uint(__builtin_amdgcn_exp2f(s[t][c][0])) + 0x8000u;
                u32 a1 = __float_as_uint(__builtin_amdgcn_exp2f(s[t][c][1])) + 0x8000u;
                u32 a2 = __float_as_uint(__builtin_amdgcn_exp2f(s[t][c][2])) + 0x8000u;
                u32 a3 = __float_as_uint(__builtin_amdgcn_exp2f(s[t][c][3])) + 0x8000u;
                uint2 pk;
                pk.x = __builtin_amdgcn_perm(a1, a0, 0x07060302u);  // [p1.hi16|p0.hi16]
                pk.y = __builtin_amdgcn_perm(a3, a2, 0x07060302u);  // [p3.hi16|p2.hi16]
                *(uint2*)&ldsP[wave][t][lrow][c * 16 + quad * 4] = pk;
            }
        // (same-wave LDS RAW: compiler inserts lgkmcnt waits; no barrier needed)
        bf16x8 pa[2][2];
#pragma unroll
        for (int t = 0; t < 2; t++) {
            pa[t][0] = *(const bf16x8*)&ldsP[wave][t][lrow][quad * 8];
            pa[t][1] = *(const bf16x8*)&ldsP[wave][t][lrow][32 + quad * 8];
        }
        // ---- row sums via MFMA (C row = q, matches Oacc rows) ----
#pragma unroll
        for (int t = 0; t < 2; t++) {
            lacc[t] = mfma16(pa[t][0], ones, lacc[t]);
            lacc[t] = mfma16(pa[t][1], ones, lacc[t]);
        }
        // ---- V fragments from LDS; O += P V ----
#pragma unroll
        for (int c = 0; c < 4; c++) {
            const int o = (c * 16 + lrow) * HD_ + fofs;
            bf16x8 v0 = *(const bf16x8*)&ldsV[cur][o];
            bf16x8 v1 = *(const bf16x8*)&ldsV[cur][o ^ 32];
#pragma unroll
            for (int t = 0; t < 2; t++) {
                Oacc[t][c] = mfma16(pa[t][0], v0, Oacc[t][c]);
                Oacc[t][c] = mfma16(pa[t][1], v1, Oacc[t][c]);
            }
        }
    }
    // ---- epilogue: lacc[t][r] is the row sum (row = quad*4+r) ----
#pragma unroll
    for (int t = 0; t < 2; t++)
#pragma unroll
        for (int r = 0; r < 4; r++) {
            const float inv = 1.0f / lacc[t][r];
            const int qrow = qbase + t * 16 + quad * 4 + r;
#pragma unroll
            for (int c = 0; c < 4; c++) {
                X2[((size_t)b * N_ + qrow) * D_ + h * HD_ + c * 16 + lrow] =
                    f2bf(Oacc[t][c][r] * inv);
            }
        }
}

extern "C" void kernel_launch(void* const* d_in, const int* in_sizes, int n_in,
                              void* d_out, int out_size, void* d_ws, size_t ws_size,
                              hipStream_t stream) {
    const float* z    = (const float*)d_in[0];
    const float* Wqkv = (const float*)d_in[1];
    const float* bqkv = (const float*)d_in[2];
    const float* Wmsa = (const float*)d_in[3];
    const float* bmsa = (const float*)d_in[4];
    float* out = (float*)d_out;

    u16* Xbf = (u16*)d_ws;
    u16* Wqb = Xbf + (size_t)NTOK * D_;
    u16* Wmb = Wqb + (size_t)NE * D_;
    u16* Qs  = Wmb + (size_t)D_ * D_;
    u16* Ks  = Qs + (size_t)B_ * H_ * N_ * HD_;
    u16* Vt  = Ks + (size_t)B_ * H_ * N_ * HD_;
    u16* X2  = Vt + (size_t)B_ * H_ * N_ * HD_;

    const int nz = NTOK * D_ / 4;
    const int nwq = NE * D_ / 4;
    const int nwm = D_ * D_ / 4;
    cvt_bf16<<<(nz + 255) / 256, 256, 0, stream>>>(z, Xbf, nz);
    cvt_bf16<<<(nwq + 255) / 256, 256, 0, stream>>>(Wqkv, Wqb, nwq);
    cvt_bf16<<<(nwm + 255) / 256, 256, 0, stream>>>(Wmsa, Wmb, nwm);

    gemm_qkv<<<dim3(NTOK / BM, NE / BN), 256, 0, stream>>>(Xbf, Wqb, bqkv, Qs, Ks, Vt);
    flash_attn<<<dim3(N_ / 128, B_ * H_), 256, 0, stream>>>(Qs, Ks, Vt, X2);
    gemm_out<<<dim3(NTOK / BM, D_ / BN), 256, 0, stream>>>(X2, Wmb, bmsa, out);
}

// Round 8
// 215.301 us; speedup vs baseline: 1.1623x; 1.0633x over previous
//
#include <hip/hip_runtime.h>

typedef unsigned short u16;
typedef unsigned int u32;
typedef __attribute__((ext_vector_type(8))) short bf16x8;
typedef __attribute__((ext_vector_type(4))) float f32x4;

#define B_ 4
#define H_ 12
#define N_ 2048
#define D_ 768
#define HD_ 64
#define NTOK (B_ * N_)      /* 8192 */
#define NE   (H_ * 3 * HD_) /* 2304 */

#define BK 64
#define CPITCH 144  /* qkv epilogue LDS C-tile pitch (16B-aligned rows) */

// 1/sqrt(64) * log2(e): Q pre-scale so attention uses exp2 (bare v_exp_f32)
#define QSCALE 0.18033688011112042f

__device__ __forceinline__ u16 f2bf(float f) {
    u32 u = __float_as_uint(f);
    u += 0x7fffu + ((u >> 16) & 1u);
    return (u16)(u >> 16);
}

__device__ __forceinline__ f32x4 mfma16(bf16x8 a, bf16x8 b, f32x4 c) {
    return __builtin_amdgcn_mfma_f32_16x16x32_bf16(a, b, c, 0, 0, 0);
}

// async global->LDS, 16B per lane. LDS dest = wave-uniform base + lane*16.
__device__ __forceinline__ void g2l16(const u16* g, u16* l) {
    __builtin_amdgcn_global_load_lds(
        (const __attribute__((address_space(1))) void*)g,
        (__attribute__((address_space(3))) void*)l, 16, 0, 0);
}

// ---------------- fused f32 -> bf16 conversion (z, Wqkv, Wmsa) ----------------
#define NZ4  (NTOK * D_ / 4)
#define NWQ4 (NE * D_ / 4)
#define NWM4 (D_ * D_ / 4)
__global__ __launch_bounds__(256) void cvt_all(const float* __restrict__ z,
                                               const float* __restrict__ Wq,
                                               const float* __restrict__ Wm,
                                               u16* __restrict__ Xbf,
                                               u16* __restrict__ Wqb,
                                               u16* __restrict__ Wmb) {
    int i = blockIdx.x * blockDim.x + threadIdx.x;
    const float* src;
    u16* dst;
    int j;
    if (i < NZ4) {
        src = z; dst = Xbf; j = i;
    } else if (i < NZ4 + NWQ4) {
        src = Wq; dst = Wqb; j = i - NZ4;
    } else if (i < NZ4 + NWQ4 + NWM4) {
        src = Wm; dst = Wmb; j = i - NZ4 - NWQ4;
    } else {
        return;
    }
    float4 v = ((const float4*)src)[j];
    u32 lo = (u32)f2bf(v.x) | ((u32)f2bf(v.y) << 16);
    u32 hi = (u32)f2bf(v.z) | ((u32)f2bf(v.w) << 16);
    ((uint2*)dst)[j] = make_uint2(lo, hi);
}

// ============ m97-structure GEMM core, tile TM x 128, BK=64 ============
#define GEMM_CORE(Xp, Wp, TM, SMELEMS)                                         \
    __shared__ u16 smem[SMELEMS];                                              \
    u16* ldsA = smem;                                                          \
    u16* ldsB = smem + (TM) * BK;                                              \
    const int tid = threadIdx.x;                                               \
    const int wave = tid >> 6, lane = tid & 63;                                \
    const int lrow = lane & 15, quad = lane >> 4;                              \
    const int mbase = blockIdx.x * (TM);                                       \
    const int nbase = blockIdx.y * 128;                                        \
    const int srow = tid >> 3;      /* 0..31 */                                \
    const int schunk = tid & 7;                                                \
    const int sk = (schunk ^ (srow & 7)) << 3; /* swizzled global k-offset */  \
    const int sdst = srow * BK + schunk * 8;   /* lane-contiguous LDS dest */  \
    const u16* gA = Xp + (size_t)(mbase + srow) * D_ + sk;                     \
    const u16* gB = Wp + (size_t)(nbase + srow) * D_ + sk;                     \
    const int m_ofs = (wave >> 1) * ((TM) / 2);                                \
    const int n_ofs = (wave & 1) * 64;                                         \
    const int e_ = lrow & 7;                                                   \
    const int offA0 = (m_ofs + lrow) * BK + ((quad ^ e_) << 3);                \
    const int offB0 = (n_ofs + lrow) * BK + ((quad ^ e_) << 3);                \
    f32x4 acc[(TM) / 32][4] = {};                                              \
    for (int kt = 0; kt < D_; kt += BK) {                                      \
        __syncthreads();                                                       \
        _Pragma("unroll") for (int i = 0; i < (TM) / 32; i++)                  \
            g2l16(gA + (size_t)(32 * i) * D_ + kt, ldsA + sdst + i * 32 * BK); \
        _Pragma("unroll") for (int i = 0; i < 4; i++)                          \
            g2l16(gB + (size_t)(32 * i) * D_ + kt, ldsB + sdst + i * 32 * BK); \
        __syncthreads();                                                       \
        _Pragma("unroll") for (int ks = 0; ks < 2; ks++) {                     \
            const int oa = offA0 ^ (ks << 5);                                  \
            const int ob = offB0 ^ (ks << 5);                                  \
            bf16x8 af[(TM) / 32], bfr[4];                                      \
            _Pragma("unroll") for (int c = 0; c < (TM) / 32; c++)              \
                af[c] = *(const bf16x8*)&ldsA[oa + c * 16 * BK];               \
            _Pragma("unroll") for (int c = 0; c < 4; c++)                      \
                bfr[c] = *(const bf16x8*)&ldsB[ob + c * 16 * BK];              \
            _Pragma("unroll") for (int i = 0; i < (TM) / 32; i++)              \
                _Pragma("unroll") for (int j = 0; j < 4; j++)                  \
                    acc[i][j] = mfma16(af[i], bfr[j], acc[i][j]);              \
        }                                                                      \
    }

// ---------------- QKV projection GEMM (128x128 tile) ----------------
// Epilogue: V-part -> packed 8B stores (4 consecutive tokens) direct from
// registers; Q/K parts -> LDS [token][feature] transpose tile (reuses smem),
// then fully-coalesced 16B stores (thread = one token's 64-feature half).
__global__ __launch_bounds__(256) void gemm_qkv(const u16* __restrict__ X,
                                                const u16* __restrict__ W,
                                                const float* __restrict__ bqkv,
                                                u16* __restrict__ Qs,
                                                u16* __restrict__ Ks,
                                                u16* __restrict__ Vt) {
    GEMM_CORE(X, W, 128, 128 * CPITCH)
    __syncthreads();  // all waves done reading ldsA/ldsB; smem becomes C-tile
    u16* ldsC = smem;
#pragma unroll
    for (int cn = 0; cn < 4; cn++) {
        const int E = nbase + n_ofs + cn * 16;  // global out-feature base
        const int h = E / 192;
        const int rr = E - h * 192;
        const int kind = rr >> 6;               // 0=Q 1=K 2=V
        const float bias = bqkv[E + lrow];
        if (kind == 2) {
            const int d = (rr & 63) + lrow;
#pragma unroll
            for (int cm = 0; cm < 4; cm++) {
                const int t0 = mbase + m_ofs + cm * 16 + quad * 4;
                const int b_ = t0 >> 11, n0 = t0 & (N_ - 1);
                const size_t bh = (size_t)(b_ * H_ + h);
                uint2 pk;
                pk.x = (u32)f2bf(acc[cm][cn][0] + bias) |
                       ((u32)f2bf(acc[cm][cn][1] + bias) << 16);
                pk.y = (u32)f2bf(acc[cm][cn][2] + bias) |
                       ((u32)f2bf(acc[cm][cn][3] + bias) << 16);
                *(uint2*)&Vt[(bh * HD_ + d) * N_ + n0] = pk;
            }
        } else {
            const int fcol = n_ofs + cn * 16 + lrow;  // block-local feature
            const float scale = (kind == 0) ? QSCALE : 1.0f;
#pragma unroll
            for (int cm = 0; cm < 4; cm++)
#pragma unroll
                for (int r = 0; r < 4; r++) {
                    const int tok = m_ofs + cm * 16 + quad * 4 + r;
                    ldsC[tok * CPITCH + fcol] =
                        f2bf((acc[cm][cn][r] + bias) * scale);
                }
        }
    }
    __syncthreads();
    // store phase: thread -> (token = tid>>1, 64-feature half = tid&1)
    {
        const int tok = tid >> 1, fh = tid & 1;
        const int gf = nbase + fh * 64;          // global feature base of half
        const int kind2 = (gf >> 6) % 3;
        if (kind2 != 2) {
            const int h2 = gf / 192;
            const int t = mbase + tok;
            const int b2 = t >> 11, n2 = t & (N_ - 1);
            u16* dst = (kind2 == 0 ? Qs : Ks) +
                       ((size_t)(b2 * H_ + h2) * N_ + n2) * HD_;
            const u16* src = &ldsC[tok * CPITCH + fh * 64];
#pragma unroll
            for (int j = 0; j < 8; j++)
                *(uint4*)&dst[j * 8] = *(const uint4*)&src[j * 8];
        }
    }
}

// ---------------- output projection GEMM (64x128 tile, 768 blocks) ----------
__global__ __launch_bounds__(256) void gemm_out(const u16* __restrict__ X2,
                                                const u16* __restrict__ W,
                                                const float* __restrict__ bmsa,
                                                float* __restrict__ out) {
    GEMM_CORE(X2, W, 64, (64 + 128) * BK)
#pragma unroll
    for (int cn = 0; cn < 4; cn++) {
        const int col = nbase + n_ofs + cn * 16 + lrow;
        const float bias = bmsa[col];
#pragma unroll
        for (int cm = 0; cm < 2; cm++) {
#pragma unroll
            for (int r = 0; r < 4; r++) {
                const int t = mbase + m_ofs + cm * 16 + quad * 4 + r;
                out[(size_t)t * D_ + col] = acc[cm][cn][r] + bias;
            }
        }
    }
}

// ---------------- Flash attention (unchanged from R7) ----------------
__global__ __launch_bounds__(256, 3) void flash_attn(const u16* __restrict__ Qs,
                                                     const u16* __restrict__ Ks,
                                                     const u16* __restrict__ Vt,
                                                     u16* __restrict__ X2) {
    __shared__ u16 ldsK[2][64 * HD_];   // 2 x 8 KB
    __shared__ u16 ldsV[2][64 * HD_];   // 2 x 8 KB
    __shared__ u16 ldsP[4][2][16][68];  // row = q (0..15), col = key (0..63)+pad
    const int tid = threadIdx.x;
    const int wave = tid >> 6, lane = tid & 63;
    const int lrow = lane & 15, quad = lane >> 4;
    const int qbase = blockIdx.x * 128 + wave * 32;
    const int bh = blockIdx.y;
    const int b = bh / H_, h = bh - b * H_;

    const u16* Kb = Ks + (size_t)bh * N_ * HD_;
    const u16* Vb = Vt + (size_t)bh * HD_ * N_;

    const int srow = tid >> 3;
    const int schunk = tid & 7;
    const int skk = (schunk ^ (srow & 7)) << 3;
    const int sdst = srow * HD_ + schunk * 8;

    bf16x8 qa[2][2];
#pragma unroll
    for (int t = 0; t < 2; t++) {
        const u16* Qb = Qs + ((size_t)bh * N_ + qbase + t * 16 + lrow) * HD_ + quad * 8;
        qa[t][0] = *(const bf16x8*)(Qb);
        qa[t][1] = *(const bf16x8*)(Qb + 32);
    }

    const int fofs = (quad ^ (lrow & 7)) << 3;
    const short onebf = (short)0x3F80;  // bf16 1.0
    const bf16x8 ones = {onebf, onebf, onebf, onebf, onebf, onebf, onebf, onebf};

    f32x4 Oacc[2][4] = {};
    f32x4 lacc[2] = {};

    {   // prologue: stage tile 0 into buffer 0
        const u16* gK = Kb + (size_t)srow * HD_ + skk;
        g2l16(gK, &ldsK[0][sdst]);
        g2l16(gK + (size_t)32 * HD_, &ldsK[0][sdst + 32 * HD_]);
        const u16* gV = Vb + (size_t)srow * N_ + skk;
        g2l16(gV, &ldsV[0][sdst]);
        g2l16(gV + (size_t)32 * N_, &ldsV[0][sdst + 32 * HD_]);
    }

    for (int it = 0; it < N_ / 64; it++) {
        const int cur = it & 1;
        __syncthreads();  // drains DMA for buf[cur]; waves done with buf[cur^1]
        if (it + 1 < N_ / 64) {
            const int kt2 = (it + 1) << 6;
            const u16* gK = Kb + (size_t)(kt2 + srow) * HD_ + skk;
            g2l16(gK, &ldsK[cur ^ 1][sdst]);
            g2l16(gK + (size_t)32 * HD_, &ldsK[cur ^ 1][sdst + 32 * HD_]);
            const u16* gV = Vb + (size_t)srow * N_ + kt2 + skk;
            g2l16(gV, &ldsV[cur ^ 1][sdst]);
            g2l16(gV + (size_t)32 * N_, &ldsV[cur ^ 1][sdst + 32 * HD_]);
        }
        // ---- K fragments from LDS (A-operand: A[m=key][k=d]) ----
        bf16x8 kf[8];
#pragma unroll
        for (int c = 0; c < 4; c++) {
            const int o = (c * 16 + lrow) * HD_ + fofs;
            kf[2 * c]     = *(const bf16x8*)&ldsK[cur][o];
            kf[2 * c + 1] = *(const bf16x8*)&ldsK[cur][o ^ 32];
        }
        // ---- S^T = K Q^T : lane holds (key=c*16+quad*4+r, q=lrow) ----
        f32x4 s[2][4] = {};
#pragma unroll
        for (int t = 0; t < 2; t++)
#pragma unroll
            for (int c = 0; c < 4; c++) {
                s[t][c] = mfma16(kf[2 * c], qa[t][0], s[t][c]);
                s[t][c] = mfma16(kf[2 * c + 1], qa[t][1], s[t][c]);
            }
        // ---- P = 2^S (raw v_exp_f32), pack 4 consecutive keys -> b64 store ----
#pragma unroll
        for (int t = 0; t < 2; t++)
#pragma unroll
            for (int c = 0; c < 4; c++) {
                u32 a0 = __float_as_uint(__builtin_amdgcn_exp2f(s[t][c][0])) + 0x8000u;
                u32 a1 = __float_as_uint(__builtin_amdgcn_exp2f(s[t][c][1])) + 0x8000u;
                u32 a2 = __float_as_uint(__builtin_amdgcn_exp2f(s[t][c][2])) + 0x8000u;
                u32 a3 = __float_as_uint(__builtin_amdgcn_exp2f(s[t][c][3])) + 0x8000u;
                uint2 pk;
                pk.x = __builtin_amdgcn_perm(a1, a0, 0x07060302u);
                pk.y = __builtin_amdgcn_perm(a3, a2, 0x07060302u);
                *(uint2*)&ldsP[wave][t][lrow][c * 16 + quad * 4] = pk;
            }
        bf16x8 pa[2][2];
#pragma unroll
        for (int t = 0; t < 2; t++) {
            pa[t][0] = *(const bf16x8*)&ldsP[wave][t][lrow][quad * 8];
            pa[t][1] = *(const bf16x8*)&ldsP[wave][t][lrow][32 + quad * 8];
        }
        // ---- row sums via MFMA (C row = q, matches Oacc rows) ----
#pragma unroll
        for (int t = 0; t < 2; t++) {
            lacc[t] = mfma16(pa[t][0], ones, lacc[t]);
            lacc[t] = mfma16(pa[t][1], ones, lacc[t]);
        }
        // ---- V fragments from LDS; O += P V ----
#pragma unroll
        for (int c = 0; c < 4; c++) {
            const int o = (c * 16 + lrow) * HD_ + fofs;
            bf16x8 v0 = *(const bf16x8*)&ldsV[cur][o];
            bf16x8 v1 = *(const bf16x8*)&ldsV[cur][o ^ 32];
#pragma unroll
            for (int t = 0; t < 2; t++) {
                Oacc[t][c] = mfma16(pa[t][0], v0, Oacc[t][c]);
                Oacc[t][c] = mfma16(pa[t][1], v1, Oacc[t][c]);
            }
        }
    }
    // ---- epilogue: lacc[t][r] is the row sum (row = quad*4+r) ----
#pragma unroll
    for (int t = 0; t < 2; t++)
#pragma unroll
        for (int r = 0; r < 4; r++) {
            const float inv = 1.0f / lacc[t][r];
            const int qrow = qbase + t * 16 + quad * 4 + r;
#pragma unroll
            for (int c = 0; c < 4; c++) {
                X2[((size_t)b * N_ + qrow) * D_ + h * HD_ + c * 16 + lrow] =
                    f2bf(Oacc[t][c][r] * inv);
            }
        }
}

extern "C" void kernel_launch(void* const* d_in, const int* in_sizes, int n_in,
                              void* d_out, int out_size, void* d_ws, size_t ws_size,
                              hipStream_t stream) {
    const float* z    = (const float*)d_in[0];
    const float* Wqkv = (const float*)d_in[1];
    const float* bqkv = (const float*)d_in[2];
    const float* Wmsa = (const float*)d_in[3];
    const float* bmsa = (const float*)d_in[4];
    float* out = (float*)d_out;

    u16* Xbf = (u16*)d_ws;
    u16* Wqb = Xbf + (size_t)NTOK * D_;
    u16* Wmb = Wqb + (size_t)NE * D_;
    u16* Qs  = Wmb + (size_t)D_ * D_;
    u16* Ks  = Qs + (size_t)B_ * H_ * N_ * HD_;
    u16* Vt  = Ks + (size_t)B_ * H_ * N_ * HD_;
    u16* X2  = Vt + (size_t)B_ * H_ * N_ * HD_;

    const int ntot = NZ4 + NWQ4 + NWM4;
    cvt_all<<<(ntot + 255) / 256, 256, 0, stream>>>(z, Wqkv, Wmsa, Xbf, Wqb, Wmb);

    gemm_qkv<<<dim3(NTOK / 128, NE / 128), 256, 0, stream>>>(Xbf, Wqb, bqkv, Qs, Ks, Vt);
    flash_attn<<<dim3(N_ / 128, B_ * H_), 256, 0, stream>>>(Qs, Ks, Vt, X2);
    gemm_out<<<dim3(NTOK / 64, D_ / 128), 256, 0, stream>>>(X2, Wmb, bmsa, out);
}

// Round 9
// 208.646 us; speedup vs baseline: 1.1993x; 1.0319x over previous
//
#include <hip/hip_runtime.h>

typedef unsigned short u16;
typedef unsigned int u32;
typedef __attribute__((ext_vector_type(8))) short bf16x8;
typedef __attribute__((ext_vector_type(4))) float f32x4;

#define B_ 4
#define H_ 12
#define N_ 2048
#define D_ 768
#define HD_ 64
#define NTOK (B_ * N_)      /* 8192 */
#define NE   (H_ * 3 * HD_) /* 2304 */

#define BK 64
#define CPITCH 144  /* qkv epilogue LDS C-tile pitch (16B-aligned rows) */

// 1/sqrt(64) * log2(e): Q pre-scale so attention uses exp2 (bare v_exp_f32)
#define QSCALE 0.18033688011112042f

__device__ __forceinline__ u16 f2bf(float f) {
    u32 u = __float_as_uint(f);
    u += 0x7fffu + ((u >> 16) & 1u);
    return (u16)(u >> 16);
}

__device__ __forceinline__ f32x4 mfma16(bf16x8 a, bf16x8 b, f32x4 c) {
    return __builtin_amdgcn_mfma_f32_16x16x32_bf16(a, b, c, 0, 0, 0);
}

// async global->LDS, 16B per lane. LDS dest = wave-uniform base + lane*16.
__device__ __forceinline__ void g2l16(const u16* g, u16* l) {
    __builtin_amdgcn_global_load_lds(
        (const __attribute__((address_space(1))) void*)g,
        (__attribute__((address_space(3))) void*)l, 16, 0, 0);
}

// ---------------- fused f32 -> bf16 conversion (z, Wqkv, Wmsa) ----------------
#define NZ4  (NTOK * D_ / 4)
#define NWQ4 (NE * D_ / 4)
#define NWM4 (D_ * D_ / 4)
__global__ __launch_bounds__(256) void cvt_all(const float* __restrict__ z,
                                               const float* __restrict__ Wq,
                                               const float* __restrict__ Wm,
                                               u16* __restrict__ Xbf,
                                               u16* __restrict__ Wqb,
                                               u16* __restrict__ Wmb) {
    int i = blockIdx.x * blockDim.x + threadIdx.x;
    const float* src;
    u16* dst;
    int j;
    if (i < NZ4) {
        src = z; dst = Xbf; j = i;
    } else if (i < NZ4 + NWQ4) {
        src = Wq; dst = Wqb; j = i - NZ4;
    } else if (i < NZ4 + NWQ4 + NWM4) {
        src = Wm; dst = Wmb; j = i - NZ4 - NWQ4;
    } else {
        return;
    }
    float4 v = ((const float4*)src)[j];
    u32 lo = (u32)f2bf(v.x) | ((u32)f2bf(v.y) << 16);
    u32 hi = (u32)f2bf(v.z) | ((u32)f2bf(v.w) << 16);
    ((uint2*)dst)[j] = make_uint2(lo, hi);
}

// ============ GEMM core v2: single-barrier double-buffered staging =========
// R8 lesson: the 2-barrier m97 K-loop stalls every iter on the full DMA
// latency (~1k cyc x 6 iters = ~half the GEMM runtime at K=768). Same fix
// that took flash 187->93: sync; DMA(t+1 -> buf^1); compute(buf).
// TM=64 -> 48 KB LDS (3 blocks/CU), qkv grid 9/CU balanced.
#define GEMM_CORE(Xp, Wp, TM, SMELEMS)                                         \
    __shared__ u16 smem[SMELEMS];                                              \
    u16* ldsA = smem;                 /* [2][TM*BK] */                         \
    u16* ldsB = smem + 2 * (TM) * BK; /* [2][128*BK] */                        \
    const int tid = threadIdx.x;                                               \
    const int wave = tid >> 6, lane = tid & 63;                                \
    const int lrow = lane & 15, quad = lane >> 4;                              \
    const int mbase = blockIdx.x * (TM);                                       \
    const int nbase = blockIdx.y * 128;                                        \
    const int srow = tid >> 3;      /* 0..31 */                                \
    const int schunk = tid & 7;                                                \
    const int sk = (schunk ^ (srow & 7)) << 3; /* swizzled global k-offset */  \
    const int sdst = srow * BK + schunk * 8;   /* lane-contiguous LDS dest */  \
    const u16* gA = Xp + (size_t)(mbase + srow) * D_ + sk;                     \
    const u16* gB = Wp + (size_t)(nbase + srow) * D_ + sk;                     \
    const int m_ofs = (wave >> 1) * ((TM) / 2);                                \
    const int n_ofs = (wave & 1) * 64;                                         \
    const int e_ = lrow & 7;                                                   \
    const int offA0 = (m_ofs + lrow) * BK + ((quad ^ e_) << 3);                \
    const int offB0 = (n_ofs + lrow) * BK + ((quad ^ e_) << 3);                \
    f32x4 acc[(TM) / 32][4] = {};                                              \
    _Pragma("unroll") for (int i = 0; i < (TM) / 32; i++)                      \
        g2l16(gA + (size_t)(32 * i) * D_, ldsA + sdst + i * 32 * BK);          \
    _Pragma("unroll") for (int i = 0; i < 4; i++)                              \
        g2l16(gB + (size_t)(32 * i) * D_, ldsB + sdst + i * 32 * BK);          \
    for (int it = 0; it < D_ / BK; it++) {                                     \
        const int cur = it & 1;                                                \
        const int abase = cur * (TM) * BK, bbase = cur * 128 * BK;             \
        __syncthreads(); /* drains DMA for buf[cur]; compute of cur^1 done */  \
        if (it + 1 < D_ / BK) {                                                \
            const int kt2 = (it + 1) * BK;                                     \
            const int nb = cur ^ 1;                                            \
            _Pragma("unroll") for (int i = 0; i < (TM) / 32; i++)              \
                g2l16(gA + (size_t)(32 * i) * D_ + kt2,                        \
                      ldsA + nb * (TM) * BK + sdst + i * 32 * BK);             \
            _Pragma("unroll") for (int i = 0; i < 4; i++)                      \
                g2l16(gB + (size_t)(32 * i) * D_ + kt2,                        \
                      ldsB + nb * 128 * BK + sdst + i * 32 * BK);              \
        }                                                                      \
        _Pragma("unroll") for (int ks = 0; ks < 2; ks++) {                     \
            const int oa = abase + (offA0 ^ (ks << 5));                        \
            const int ob = bbase + (offB0 ^ (ks << 5));                        \
            bf16x8 af[(TM) / 32], bfr[4];                                      \
            _Pragma("unroll") for (int c = 0; c < (TM) / 32; c++)              \
                af[c] = *(const bf16x8*)&ldsA[oa + c * 16 * BK];               \
            _Pragma("unroll") for (int c = 0; c < 4; c++)                      \
                bfr[c] = *(const bf16x8*)&ldsB[ob + c * 16 * BK];              \
            _Pragma("unroll") for (int i = 0; i < (TM) / 32; i++)              \
                _Pragma("unroll") for (int j = 0; j < 4; j++)                  \
                    acc[i][j] = mfma16(af[i], bfr[j], acc[i][j]);              \
        }                                                                      \
    }

// ---------------- QKV projection GEMM (64x128 tile, grid 2304 = 9/CU) -------
__global__ __launch_bounds__(256) void gemm_qkv(const u16* __restrict__ X,
                                                const u16* __restrict__ W,
                                                const float* __restrict__ bqkv,
                                                u16* __restrict__ Qs,
                                                u16* __restrict__ Ks,
                                                u16* __restrict__ Vt) {
    GEMM_CORE(X, W, 64, 24576)
    __syncthreads();  // all waves done reading ldsA/ldsB; smem becomes C-tile
    u16* ldsC = smem;
#pragma unroll
    for (int cn = 0; cn < 4; cn++) {
        const int E = nbase + n_ofs + cn * 16;  // global out-feature base
        const int h = E / 192;
        const int rr = E - h * 192;
        const int kind = rr >> 6;               // 0=Q 1=K 2=V
        const float bias = bqkv[E + lrow];
        if (kind == 2) {
            const int d = (rr & 63) + lrow;
#pragma unroll
            for (int cm = 0; cm < 2; cm++) {
                const int t0 = mbase + m_ofs + cm * 16 + quad * 4;
                const int b_ = t0 >> 11, n0 = t0 & (N_ - 1);
                const size_t bh = (size_t)(b_ * H_ + h);
                uint2 pk;
                pk.x = (u32)f2bf(acc[cm][cn][0] + bias) |
                       ((u32)f2bf(acc[cm][cn][1] + bias) << 16);
                pk.y = (u32)f2bf(acc[cm][cn][2] + bias) |
                       ((u32)f2bf(acc[cm][cn][3] + bias) << 16);
                *(uint2*)&Vt[(bh * HD_ + d) * N_ + n0] = pk;
            }
        } else {
            const int fcol = n_ofs + cn * 16 + lrow;  // block-local feature
            const float scale = (kind == 0) ? QSCALE : 1.0f;
#pragma unroll
            for (int cm = 0; cm < 2; cm++)
#pragma unroll
                for (int r = 0; r < 4; r++) {
                    const int tok = m_ofs + cm * 16 + quad * 4 + r;
                    ldsC[tok * CPITCH + fcol] =
                        f2bf((acc[cm][cn][r] + bias) * scale);
                }
        }
    }
    __syncthreads();
    // store phase: thread -> (token = tid>>2, sub = half(64f) x j-half)
    {
        const int tok = tid >> 2, sub = tid & 3;
        const int fh = sub >> 1, jh = sub & 1;
        const int gf = nbase + fh * 64;          // global feature base of half
        const int kind2 = (gf >> 6) % 3;
        if (kind2 != 2) {
            const int h2 = gf / 192;
            const int t = mbase + tok;
            const int b2 = t >> 11, n2 = t & (N_ - 1);
            u16* dst = (kind2 == 0 ? Qs : Ks) +
                       ((size_t)(b2 * H_ + h2) * N_ + n2) * HD_;
            const u16* src = &ldsC[tok * CPITCH + fh * 64];
#pragma unroll
            for (int j = 0; j < 4; j++)
                *(uint4*)&dst[(jh * 4 + j) * 8] =
                    *(const uint4*)&src[(jh * 4 + j) * 8];
        }
    }
}

// ---------------- output projection GEMM (64x128 tile, 768 blocks) ----------
__global__ __launch_bounds__(256) void gemm_out(const u16* __restrict__ X2,
                                                const u16* __restrict__ W,
                                                const float* __restrict__ bmsa,
                                                float* __restrict__ out) {
    GEMM_CORE(X2, W, 64, 24576)
#pragma unroll
    for (int cn = 0; cn < 4; cn++) {
        const int col = nbase + n_ofs + cn * 16 + lrow;
        const float bias = bmsa[col];
#pragma unroll
        for (int cm = 0; cm < 2; cm++) {
#pragma unroll
            for (int r = 0; r < 4; r++) {
                const int t = mbase + m_ofs + cm * 16 + quad * 4 + r;
                out[(size_t)t * D_ + col] = acc[cm][cn][r] + bias;
            }
        }
    }
}

// ---------------- Flash attention (R7 + truncate-pack P) ----------------
__global__ __launch_bounds__(256, 3) void flash_attn(const u16* __restrict__ Qs,
                                                     const u16* __restrict__ Ks,
                                                     const u16* __restrict__ Vt,
                                                     u16* __restrict__ X2) {
    __shared__ u16 ldsK[2][64 * HD_];   // 2 x 8 KB
    __shared__ u16 ldsV[2][64 * HD_];   // 2 x 8 KB
    __shared__ u16 ldsP[4][2][16][68];  // row = q (0..15), col = key (0..63)+pad
    const int tid = threadIdx.x;
    const int wave = tid >> 6, lane = tid & 63;
    const int lrow = lane & 15, quad = lane >> 4;
    const int qbase = blockIdx.x * 128 + wave * 32;
    const int bh = blockIdx.y;
    const int b = bh / H_, h = bh - b * H_;

    const u16* Kb = Ks + (size_t)bh * N_ * HD_;
    const u16* Vb = Vt + (size_t)bh * HD_ * N_;

    const int srow = tid >> 3;
    const int schunk = tid & 7;
    const int skk = (schunk ^ (srow & 7)) << 3;
    const int sdst = srow * HD_ + schunk * 8;

    bf16x8 qa[2][2];
#pragma unroll
    for (int t = 0; t < 2; t++) {
        const u16* Qb = Qs + ((size_t)bh * N_ + qbase + t * 16 + lrow) * HD_ + quad * 8;
        qa[t][0] = *(const bf16x8*)(Qb);
        qa[t][1] = *(const bf16x8*)(Qb + 32);
    }

    const int fofs = (quad ^ (lrow & 7)) << 3;
    const short onebf = (short)0x3F80;  // bf16 1.0
    const bf16x8 ones = {onebf, onebf, onebf, onebf, onebf, onebf, onebf, onebf};

    f32x4 Oacc[2][4] = {};
    f32x4 lacc[2] = {};

    {   // prologue: stage tile 0 into buffer 0
        const u16* gK = Kb + (size_t)srow * HD_ + skk;
        g2l16(gK, &ldsK[0][sdst]);
        g2l16(gK + (size_t)32 * HD_, &ldsK[0][sdst + 32 * HD_]);
        const u16* gV = Vb + (size_t)srow * N_ + skk;
        g2l16(gV, &ldsV[0][sdst]);
        g2l16(gV + (size_t)32 * N_, &ldsV[0][sdst + 32 * HD_]);
    }

    for (int it = 0; it < N_ / 64; it++) {
        const int cur = it & 1;
        __syncthreads();  // drains DMA for buf[cur]; waves done with buf[cur^1]
        if (it + 1 < N_ / 64) {
            const int kt2 = (it + 1) << 6;
            const u16* gK = Kb + (size_t)(kt2 + srow) * HD_ + skk;
            g2l16(gK, &ldsK[cur ^ 1][sdst]);
            g2l16(gK + (size_t)32 * HD_, &ldsK[cur ^ 1][sdst + 32 * HD_]);
            const u16* gV = Vb + (size_t)srow * N_ + kt2 + skk;
            g2l16(gV, &ldsV[cur ^ 1][sdst]);
            g2l16(gV + (size_t)32 * N_, &ldsV[cur ^ 1][sdst + 32 * HD_]);
        }
        // ---- K fragments from LDS (A-operand: A[m=key][k=d]) ----
        bf16x8 kf[8];
#pragma unroll
        for (int c = 0; c < 4; c++) {
            const int o = (c * 16 + lrow) * HD_ + fofs;
            kf[2 * c]     = *(const bf16x8*)&ldsK[cur][o];
            kf[2 * c + 1] = *(const bf16x8*)&ldsK[cur][o ^ 32];
        }
        // ---- S^T = K Q^T : lane holds (key=c*16+quad*4+r, q=lrow) ----
        f32x4 s[2][4] = {};
#pragma unroll
        for (int t = 0; t < 2; t++)
#pragma unroll
            for (int c = 0; c < 4; c++) {
                s[t][c] = mfma16(kf[2 * c], qa[t][0], s[t][c]);
                s[t][c] = mfma16(kf[2 * c + 1], qa[t][1], s[t][c]);
            }
        // ---- P = 2^S (raw v_exp_f32), truncate-pack pairs -> b64 store ----
        // (truncation bias cancels: l sums the same truncated bf16 P)
#pragma unroll
        for (int t = 0; t < 2; t++)
#pragma unroll
            for (int c = 0; c < 4; c++) {
                u32 b0 = __float_as_uint(__builtin_amdgcn_exp2f(s[t][c][0]));
                u32 b1 = __float_as_uint(__builtin_amdgcn_exp2f(s[t][c][1]));
                u32 b2 = __float_as_uint(__builtin_amdgcn_exp2f(s[t][c][2]));
                u32 b3 = __float_as_uint(__builtin_amdgcn_exp2f(s[t][c][3]));
                uint2 pk;
                pk.x = __builtin_amdgcn_perm(b1, b0, 0x07060302u);
                pk.y = __builtin_amdgcn_perm(b3, b2, 0x07060302u);
                *(uint2*)&ldsP[wave][t][lrow][c * 16 + quad * 4] = pk;
            }
        bf16x8 pa[2][2];
#pragma unroll
        for (int t = 0; t < 2; t++) {
            pa[t][0] = *(const bf16x8*)&ldsP[wave][t][lrow][quad * 8];
            pa[t][1] = *(const bf16x8*)&ldsP[wave][t][lrow][32 + quad * 8];
        }
        // ---- row sums via MFMA (C row = q, matches Oacc rows) ----
#pragma unroll
        for (int t = 0; t < 2; t++) {
            lacc[t] = mfma16(pa[t][0], ones, lacc[t]);
            lacc[t] = mfma16(pa[t][1], ones, lacc[t]);
        }
        // ---- V fragments from LDS; O += P V ----
#pragma unroll
        for (int c = 0; c < 4; c++) {
            const int o = (c * 16 + lrow) * HD_ + fofs;
            bf16x8 v0 = *(const bf16x8*)&ldsV[cur][o];
            bf16x8 v1 = *(const bf16x8*)&ldsV[cur][o ^ 32];
#pragma unroll
            for (int t = 0; t < 2; t++) {
                Oacc[t][c] = mfma16(pa[t][0], v0, Oacc[t][c]);
                Oacc[t][c] = mfma16(pa[t][1], v1, Oacc[t][c]);
            }
        }
    }
    // ---- epilogue: lacc[t][r] is the row sum (row = quad*4+r) ----
#pragma unroll
    for (int t = 0; t < 2; t++)
#pragma unroll
        for (int r = 0; r < 4; r++) {
            const float inv = 1.0f / lacc[t][r];
            const int qrow = qbase + t * 16 + quad * 4 + r;
#pragma unroll
            for (int c = 0; c < 4; c++) {
                X2[((size_t)b * N_ + qrow) * D_ + h * HD_ + c * 16 + lrow] =
                    f2bf(Oacc[t][c][r] * inv);
            }
        }
}

extern "C" void kernel_launch(void* const* d_in, const int* in_sizes, int n_in,
                              void* d_out, int out_size, void* d_ws, size_t ws_size,
                              hipStream_t stream) {
    const float* z    = (const float*)d_in[0];
    const float* Wqkv = (const float*)d_in[1];
    const float* bqkv = (const float*)d_in[2];
    const float* Wmsa = (const float*)d_in[3];
    const float* bmsa = (const float*)d_in[4];
    float* out = (float*)d_out;

    u16* Xbf = (u16*)d_ws;
    u16* Wqb = Xbf + (size_t)NTOK * D_;
    u16* Wmb = Wqb + (size_t)NE * D_;
    u16* Qs  = Wmb + (size_t)D_ * D_;
    u16* Ks  = Qs + (size_t)B_ * H_ * N_ * HD_;
    u16* Vt  = Ks + (size_t)B_ * H_ * N_ * HD_;
    u16* X2  = Vt + (size_t)B_ * H_ * N_ * HD_;

    const int ntot = NZ4 + NWQ4 + NWM4;
    cvt_all<<<(ntot + 255) / 256, 256, 0, stream>>>(z, Wqkv, Wmsa, Xbf, Wqb, Wmb);

    gemm_qkv<<<dim3(NTOK / 64, NE / 128), 256, 0, stream>>>(Xbf, Wqb, bqkv, Qs, Ks, Vt);
    flash_attn<<<dim3(N_ / 128, B_ * H_), 256, 0, stream>>>(Qs, Ks, Vt, X2);
    gemm_out<<<dim3(NTOK / 64, D_ / 128), 256, 0, stream>>>(X2, Wmb, bmsa, out);
}